// Round 7
// baseline (207.817 us; speedup 1.0000x reference)
//
#include <hip/hip_runtime.h>
#include <stdint.h>

typedef __attribute__((ext_vector_type(4))) float  f32x4;
typedef __attribute__((ext_vector_type(8))) __bf16 bf16x8;

constexpr int F_DIM = 128;   // feature dim
constexpr int KC    = 256;   // number of centers
// u = max(sq, 1e-24)^(-1/(M-1)),  M = 1.7  ->  exponent on sq is -1/0.7
constexpr float ALPHA = -1.4285714285714286f;

// ---------------------------------------------------------------------------
// Pre-kernel: centers (fp32, row-major) -> d_ws as {linear bf16 image (64 KiB),
// c2 table (1 KiB)}. Runs once per launch; stays hot in every XCD's L2.
// ---------------------------------------------------------------------------
__global__ __launch_bounds__(64) void fcm_prep(
        const float* __restrict__ centers,
        __bf16* __restrict__ wsB,
        float* __restrict__ wsC2)
{
    const int j    = blockIdx.x;     // center 0..255
    const int lane = threadIdx.x;    // 0..63, handles elements 2*lane, 2*lane+1
    const float2 v = *(const float2*)(centers + j * F_DIM + 2 * lane);
    wsB[j * F_DIM + 2 * lane]     = (__bf16)v.x;
    wsB[j * F_DIM + 2 * lane + 1] = (__bf16)v.y;

    float ss = v.x * v.x + v.y * v.y;
    ss += __shfl_xor(ss, 1);  ss += __shfl_xor(ss, 2);  ss += __shfl_xor(ss, 4);
    ss += __shfl_xor(ss, 8);  ss += __shfl_xor(ss, 16); ss += __shfl_xor(ss, 32);
    if (lane == 0) wsC2[j] = ss;
}

// ---------------------------------------------------------------------------
// Main kernel: NO LDS, NO barriers. Center fragments are read per-wave
// directly from the L2-resident bf16 image; waves are fully independent.
// ---------------------------------------------------------------------------
__global__ __launch_bounds__(256) void fcm_kernel(
        const float* __restrict__ x,
        const __bf16* __restrict__ wsB,
        const float* __restrict__ wsC2,
        float* __restrict__ out)
{
    const int tid  = threadIdx.x;
    const int lane = tid & 63;
    const int wave = tid >> 6;

    // ---------- load x fragments (16 rows per wave) + exact fp32 x2 ----------
    const int rbase = blockIdx.x * 64 + wave * 16;
    const int lrow  = lane & 15;   // x-row within the wave's 16-row tile
    const int kq    = lane >> 4;   // k-quarter 0..3
    const float* xrow = x + (long long)(rbase + lrow) * F_DIM + kq * 8;

    bf16x8 fragX[4];
    float x2 = 0.f;
    #pragma unroll
    for (int kb = 0; kb < 4; ++kb) {
        f32x4 a = *(const f32x4*)(xrow + kb * 32);
        f32x4 b = *(const f32x4*)(xrow + kb * 32 + 4);
        x2 += a.x*a.x + a.y*a.y + a.z*a.z + a.w*a.w;
        x2 += b.x*b.x + b.y*b.y + b.z*b.z + b.w*b.w;
        union { __bf16 bh[8]; bf16x8 v; } pk;
        pk.bh[0] = (__bf16)a.x; pk.bh[1] = (__bf16)a.y;
        pk.bh[2] = (__bf16)a.z; pk.bh[3] = (__bf16)a.w;
        pk.bh[4] = (__bf16)b.x; pk.bh[5] = (__bf16)b.y;
        pk.bh[6] = (__bf16)b.z; pk.bh[7] = (__bf16)b.w;
        fragX[kb] = pk.v;
    }
    // lanes {l, l^16, l^32, l^48} hold disjoint k-quarters of row (lane&15)
    x2 += __shfl_xor(x2, 16);
    x2 += __shfl_xor(x2, 32);
    // every lane now holds ||x_row||^2 for its row (lane&15)

    // ---------- MFMA: D[j_center][i_xrow], A = centers (L2 image), B = x ------
    // C/D layout: col = lane&15 -> x-row; row = kq*4 + r -> center within tile.
    // fc fragment for (nt,kb): center row nt*16+lrow, features kb*32 + kq*8..+8
    // -> 1 KB coalesced load per wave instruction, L1/L2-hit after warm-up.
    f32x4 acc[16];
    #pragma unroll
    for (int nt = 0; nt < 16; ++nt) acc[nt] = f32x4{0.f, 0.f, 0.f, 0.f};

    const __bf16* cbase = wsB + lrow * F_DIM + kq * 8;
    #pragma unroll
    for (int nt = 0; nt < 16; ++nt) {
        const __bf16* crow = cbase + nt * 16 * F_DIM;
        #pragma unroll
        for (int kb = 0; kb < 4; ++kb) {
            bf16x8 fc = *(const bf16x8*)(crow + kb * 32);
            acc[nt] = __builtin_amdgcn_mfma_f32_16x16x32_bf16(fc, fragX[kb], acc[nt], 0, 0, 0);
        }
    }

    // ---------- epilogue: sq -> u = sq^ALPHA, row-normalize, dwordx4 store ----
    float rowsum = 0.f;
    #pragma unroll
    for (int nt = 0; nt < 16; ++nt) {
        f32x4 c2v = *(const f32x4*)(wsC2 + nt * 16 + kq * 4);
        #pragma unroll
        for (int r = 0; r < 4; ++r) {
            float sq = fmaxf(x2 + c2v[r] - 2.0f * acc[nt][r], 1e-24f);
            float u  = __builtin_amdgcn_exp2f(ALPHA * __builtin_amdgcn_logf(sq));
            acc[nt][r] = u;
            rowsum += u;
        }
    }
    // lanes l, l^16, l^32, l^48 hold disjoint center-subsets of the same x-row
    rowsum += __shfl_xor(rowsum, 16);
    rowsum += __shfl_xor(rowsum, 32);
    const float rinv = __builtin_amdgcn_rcpf(rowsum);

    float* orow = out + (long long)(rbase + lrow) * KC + kq * 4;
    #pragma unroll
    for (int nt = 0; nt < 16; ++nt) {
        f32x4 v = acc[nt] * rinv;
        *(f32x4*)(orow + nt * 16) = v;
    }
}

extern "C" void kernel_launch(void* const* d_in, const int* in_sizes, int n_in,
                              void* d_out, int out_size, void* d_ws, size_t ws_size,
                              hipStream_t stream) {
    const float* x       = (const float*)d_in[0];
    const float* centers = (const float*)d_in[1];
    float* out           = (float*)d_out;

    __bf16* wsB  = (__bf16*)d_ws;                 // 64 KiB linear bf16 image
    float*  wsC2 = (float*)((char*)d_ws + KC * F_DIM * 2); // 1 KiB c2 table

    const int N      = in_sizes[0] / F_DIM;   // 262144
    const int blocks = N / 64;                // 64 rows per 256-thread block

    fcm_prep<<<KC, 64, 0, stream>>>(centers, wsB, wsC2);
    fcm_kernel<<<blocks, 256, 0, stream>>>(x, wsB, wsC2, out);
}